// Round 3
// baseline (14897.697 us; speedup 1.0000x reference)
//
#include <hip/hip_runtime.h>
#include <cstdint>
#include <cstddef>

// Problem constants: V=50000, E=300, NF=1, H=256, B=128, TH=32, TB=512, NC=4.
#define H_    256
#define NG    768      // 512 gate cols (r|u) + 256 candidate cols, packed
#define BATCH 128
#define TH_   32
#define TB_   512
#define E_    300
#define RPB   16       // batch rows per gru block
#define NBLK  (BATCH / RPB)   // 8 gru blocks

typedef _Float16 half8 __attribute__((ext_vector_type(8)));
typedef float    floatx4 __attribute__((ext_vector_type(4)));

// frag position of element (m, k) in packed-per-ktile LDS buffers:
// pos = (kt*64 + quad*16 + m)*8 + j,  kt=k>>5, quad=(k&31)>>3, j=k&7
__device__ __forceinline__ int fragpos(int m, int k) {
  return (((k >> 5) * 64) + (((k & 31) >> 3) * 16) + m) * 8 + (k & 7);
}

// ---------------------------------------------------------------------------
// Pack input-projection weights (fp32) + bias. j<512 -> Wg col j; else Wc.
// ---------------------------------------------------------------------------
__global__ __launch_bounds__(256) void pack_k(
    const float* __restrict__ Wg, const float* __restrict__ bg,
    const float* __restrict__ Wc, const float* __restrict__ bc, int din,
    float* __restrict__ Bx, float* __restrict__ bias)
{
  int idx = blockIdx.x * 256 + threadIdx.x;
  if (idx < NG) bias[idx] = (idx < 2 * H_) ? bg[idx] : bc[idx - 2 * H_];
  int tot = din * NG;
  if (idx >= tot) return;
  int k = idx / NG, j = idx % NG;
  float v = (j < 2 * H_) ? Wg[k * 2 * H_ + j] : Wc[k * H_ + (j - 2 * H_)];
  Bx[(size_t)k * NG + j] = v;
}

// ---------------------------------------------------------------------------
// Pack recurrent weights into fp16 MFMA B-fragment order.
// Tiles: [0,256): gate cols, nt=tile>>3, kt=tile&7, col base nt*16 (Wg).
//        [256,384): candidate cols (Wc). 1 KB per tile (64 lanes x 16 B).
// B-frag: lane l, elem j -> W[k0 + (l>>4)*8 + j][n0 + (l&15)], k0=kt*32.
// ---------------------------------------------------------------------------
__global__ __launch_bounds__(256) void pack_w(
    const float* __restrict__ Wg, const float* __restrict__ Wc, int din,
    _Float16* __restrict__ wpk)
{
  int idx = blockIdx.x * 256 + threadIdx.x;
  if (idx >= 384 * 64) return;
  int tile = idx >> 6, lane = idx & 63;
  const float* W; int ncols, nt, kt;
  if (tile < 256) { nt = tile >> 3; kt = tile & 7; W = Wg; ncols = 2 * H_; }
  else { int tt = tile - 256; nt = tt >> 3; kt = tt & 7; W = Wc; ncols = H_; }
  int n = nt * 16 + (lane & 15);
  int kb = kt * 32 + (lane >> 4) * 8;
  _Float16* dst = wpk + ((size_t)(tile * 64 + lane)) * 8;
#pragma unroll
  for (int j = 0; j < 8; ++j)
    dst[j] = (_Float16)W[(size_t)(din + kb + j) * ncols + n];
}

// ---------------------------------------------------------------------------
// seqlen[b] = #nonzero ids in row b (valid steps form a prefix).
// ---------------------------------------------------------------------------
__global__ __launch_bounds__(256) void seq_k(const int* __restrict__ ids, int T,
                                             int* __restrict__ seq)
{
  __shared__ int red[256];
  int b = blockIdx.x, tid = threadIdx.x;
  int cnt = 0;
  for (int t = tid; t < T; t += 256) cnt += (ids[b * T + t] != 0) ? 1 : 0;
  red[tid] = cnt;
  __syncthreads();
  for (int s = 128; s > 0; s >>= 1) {
    if (tid < s) red[tid] += red[tid + s];
    __syncthreads();
  }
  if (tid == 0) seq[b] = red[0];
}

// ---------------------------------------------------------------------------
// Input-projection GEMM over a time-chunk (fp32):
//   G[row, 0:768] = A[row, :K] @ Bp[K, 768] + bias, row = b*tc + tlocal.
// ---------------------------------------------------------------------------
__global__ __launch_bounds__(256) void gemm_in(
    const float* __restrict__ Adir, const int* __restrict__ ids,
    const float* __restrict__ emb,
    const float* __restrict__ Bp, const float* __restrict__ bias,
    float* __restrict__ G, int nrows, int K, int t0, int tc, int T)
{
  __shared__ float As[16][68];
  __shared__ float Bs[16][64];
  const int tid = threadIdx.x;
  const int m0 = blockIdx.x * 64;
  const int n0 = blockIdx.y * 64;
  const int tm = (tid >> 4) * 4;
  const int tn = (tid & 15) * 4;
  const int la_r = tid >> 4;
  const int la_k = tid & 15;
  const int lb_n = tid & 63;
  const int lb_k = tid >> 6;
  float acc[4][4] = {{0.f}};

  for (int k0 = 0; k0 < K; k0 += 16) {
#pragma unroll
    for (int p = 0; p < 4; ++p) {
      int r = p * 16 + la_r;
      int row = m0 + r;
      int kg = k0 + la_k;
      float v = 0.f;
      if (row < nrows && kg < K) {
        if (Adir) v = Adir[(size_t)row * K + kg];
        else {
          int b = row / tc, tl = row % tc;
          v = emb[(size_t)ids[b * T + t0 + tl] * K + kg];
        }
      }
      As[la_k][r] = v;
    }
#pragma unroll
    for (int p = 0; p < 4; ++p) {
      int kl = p * 4 + lb_k;
      int kg = k0 + kl;
      Bs[kl][lb_n] = (kg < K) ? Bp[(size_t)kg * NG + n0 + lb_n] : 0.f;
    }
    __syncthreads();
#pragma unroll
    for (int kk = 0; kk < 16; ++kk) {
      float a0 = As[kk][tm + 0], a1 = As[kk][tm + 1];
      float a2 = As[kk][tm + 2], a3 = As[kk][tm + 3];
      float b0 = Bs[kk][tn + 0], b1 = Bs[kk][tn + 1];
      float b2 = Bs[kk][tn + 2], b3 = Bs[kk][tn + 3];
      acc[0][0] += a0 * b0; acc[0][1] += a0 * b1; acc[0][2] += a0 * b2; acc[0][3] += a0 * b3;
      acc[1][0] += a1 * b0; acc[1][1] += a1 * b1; acc[1][2] += a1 * b2; acc[1][3] += a1 * b3;
      acc[2][0] += a2 * b0; acc[2][1] += a2 * b1; acc[2][2] += a2 * b2; acc[2][3] += a2 * b3;
      acc[3][0] += a3 * b0; acc[3][1] += a3 * b1; acc[3][2] += a3 * b2; acc[3][3] += a3 * b3;
    }
    __syncthreads();
  }
#pragma unroll
  for (int i = 0; i < 4; ++i) {
    int row = m0 + tm + i;
    if (row < nrows) {
#pragma unroll
      for (int j = 0; j < 4; ++j)
        G[(size_t)row * NG + n0 + tn + j] = acc[i][j] + bias[n0 + tn + j];
    }
  }
}

// ---------------------------------------------------------------------------
// MFMA GRU recurrence over a time-chunk. 8 blocks x 512 thr; block bid owns
// batch rows bid*16..bid*16+15. Per step: [16,256]@[256,768] in fp16 MFMA,
// h kept exact as fp16 hi+lo split (2 MFMAs per product). Weights stream
// L2->VGPR in frag order; h/rh live in LDS in frag order (conflict-free
// ds_read_b128). fp32 Gx (precomputed x-projection+bias) added in epilogue.
// ---------------------------------------------------------------------------
__global__ __launch_bounds__(512) void gru_mfma(
    const float* __restrict__ G, const _Float16* __restrict__ Wpk,
    const int* __restrict__ seq, float* __restrict__ outp,
    float* __restrict__ state, int t0, int tc)
{
  __shared__ __align__(16) _Float16 hpk[2][4096];   // h hi/lo, frag order
  __shared__ __align__(16) _Float16 rpk[2][4096];   // r*h hi/lo, frag order
  __shared__ float uf[16][260];                     // u gate, fp32
  __shared__ int seqL[16];

  const int bid = blockIdx.x;
  const int tid = threadIdx.x;
  const int w = tid >> 6, lane = tid & 63;
  const int quad = lane >> 4, l15 = lane & 15;

  if (tid < 16) seqL[tid] = seq[bid * RPB + tid];
  for (int idx = tid; idx < 4096; idx += 512) {
    int m = idx & 15, k = idx >> 4;
    float v = (t0 == 0) ? 0.f : state[(size_t)(bid * RPB + m) * H_ + k];
    _Float16 hi = (_Float16)v;
    int pos = fragpos(m, k);
    hpk[0][pos] = hi;
    hpk[1][pos] = (_Float16)(v - (float)hi);
  }
  __syncthreads();
  int Smax = 0;
#pragma unroll
  for (int i = 0; i < 16; ++i) Smax = max(Smax, seqL[i]);
  int steps = Smax - t0;
  if (steps < 0) steps = 0;
  if (steps > tc) steps = tc;

  for (int t = 0; t < steps; ++t) {
    const int tg = t0 + t;
    const size_t gbase = ((size_t)bid * RPB * tc + t) * NG;
    // ---------------- phase A: 512 gate cols ----------------
    floatx4 acc[4] = {};
#pragma unroll
    for (int kt = 0; kt < 8; ++kt) {
      half8 ahi = *(const half8*)&hpk[0][(kt * 64 + lane) * 8];
      half8 alo = *(const half8*)&hpk[1][(kt * 64 + lane) * 8];
#pragma unroll
      for (int s = 0; s < 4; ++s) {
        half8 bf = *(const half8*)&Wpk[(size_t)(((w * 4 + s) * 8 + kt) * 64 + lane) * 8];
        acc[s] = __builtin_amdgcn_mfma_f32_16x16x32_f16(ahi, bf, acc[s], 0, 0, 0);
        acc[s] = __builtin_amdgcn_mfma_f32_16x16x32_f16(alo, bf, acc[s], 0, 0, 0);
      }
    }
    if (w < 4) {           // r gates: cols 0..255
#pragma unroll
      for (int s = 0; s < 4; ++s) {
        int k = w * 64 + s * 16 + l15;
#pragma unroll
        for (int r = 0; r < 4; ++r) {
          int row = quad * 4 + r;
          float pre = acc[s][r] + G[gbase + (size_t)row * tc * NG + k];
          float gate = 1.f / (1.f + __expf(-pre));
          int pos = fragpos(row, k);
          float hold = (float)hpk[0][pos] + (float)hpk[1][pos];
          float rh = gate * hold;
          _Float16 hi = (_Float16)rh;
          rpk[0][pos] = hi;
          rpk[1][pos] = (_Float16)(rh - (float)hi);
        }
      }
    } else {               // u gates: cols 256..511
#pragma unroll
      for (int s = 0; s < 4; ++s) {
        int k = (w - 4) * 64 + s * 16 + l15;
        int col = 256 + k;
#pragma unroll
        for (int r = 0; r < 4; ++r) {
          int row = quad * 4 + r;
          float pre = acc[s][r] + G[gbase + (size_t)row * tc * NG + col];
          uf[row][k] = 1.f / (1.f + __expf(-pre));
        }
      }
    }
    __syncthreads();
    // ---------------- phase B: 256 candidate cols ----------------
    floatx4 accB[2] = {};
#pragma unroll
    for (int kt = 0; kt < 8; ++kt) {
      half8 ahi = *(const half8*)&rpk[0][(kt * 64 + lane) * 8];
      half8 alo = *(const half8*)&rpk[1][(kt * 64 + lane) * 8];
#pragma unroll
      for (int s = 0; s < 2; ++s) {
        half8 bf = *(const half8*)&Wpk[(size_t)((256 + (w * 2 + s) * 8 + kt) * 64 + lane) * 8];
        accB[s] = __builtin_amdgcn_mfma_f32_16x16x32_f16(ahi, bf, accB[s], 0, 0, 0);
        accB[s] = __builtin_amdgcn_mfma_f32_16x16x32_f16(alo, bf, accB[s], 0, 0, 0);
      }
    }
#pragma unroll
    for (int s = 0; s < 2; ++s) {
      int k = w * 32 + s * 16 + l15;
#pragma unroll
      for (int r = 0; r < 4; ++r) {
        int row = quad * 4 + r;
        float pre = accB[s][r] + G[gbase + (size_t)row * tc * NG + 512 + k];
        float e2 = __expf(2.f * pre);
        float c = 1.f - 2.f / (1.f + e2);      // tanh
        int pos = fragpos(row, k);
        float hold = (float)hpk[0][pos] + (float)hpk[1][pos];
        float u = uf[row][k];
        float hn = u * hold + (1.f - u) * c;
        bool valid = tg < seqL[row];
        if (!valid) hn = hold;
        _Float16 hi = (_Float16)hn;
        hpk[0][pos] = hi;
        hpk[1][pos] = (_Float16)(hn - (float)hi);
        if (outp)
          outp[((size_t)(bid * RPB + row) * tc + t) * H_ + k] = valid ? hn : 0.f;
      }
    }
    __syncthreads();
  }
  for (int idx = tid; idx < 4096; idx += 512) {
    int m = idx & 15, k = idx >> 4;
    int pos = fragpos(m, k);
    state[(size_t)(bid * RPB + m) * H_ + k] = (float)hpk[0][pos] + (float)hpk[1][pos];
  }
}

// ---------------------------------------------------------------------------
// Final prediction: out[b, c] = [h_head | h_body] @ W_pred + b_pred.
// ---------------------------------------------------------------------------
__global__ __launch_bounds__(512) void pred_k(
    const float* __restrict__ hh, const float* __restrict__ hb,
    const float* __restrict__ Wp, const float* __restrict__ bpred,
    float* __restrict__ out)
{
  int tid = threadIdx.x;
  int b = tid >> 2, c = tid & 3;
  float acc = bpred[c];
  for (int k = 0; k < H_; ++k) acc += hh[b * H_ + k] * Wp[k * 4 + c];
  for (int k = 0; k < H_; ++k) acc += hb[b * H_ + k] * Wp[(H_ + k) * 4 + c];
  out[b * 4 + c] = acc;
}

// ---------------------------------------------------------------------------
extern "C" void kernel_launch(void* const* d_in, const int* in_sizes, int n_in,
                              void* d_out, int out_size, void* d_ws, size_t ws_size,
                              hipStream_t stream)
{
  (void)in_sizes; (void)n_in; (void)out_size;
  const int*   idsH = (const int*)  d_in[0];
  const int*   idsB = (const int*)  d_in[1];
  const float* emb  = (const float*)d_in[2];
  const float* Wp   = (const float*)d_in[3];
  const float* bp   = (const float*)d_in[4];
  const float* W[4][4];   // [hd0,hd1,bd0,bd1][Wg,bg,Wc,bc]
  for (int s = 0; s < 4; ++s)
    for (int q = 0; q < 4; ++q)
      W[s][q] = (const float*)d_in[5 + s * 4 + q];

  // choose time-chunk CH to fit ws_size
  const size_t fixed_f = 2200000;
  int CH = 128;
  while (CH > 8 && (fixed_f + (size_t)BATCH * CH * (NG + H_)) * 4 > ws_size)
    CH >>= 1;
  const int CHH = (CH < TH_) ? CH : TH_;

  float* wbase = (float*)d_ws;
  size_t off = 0;
  auto alloc = [&](size_t n) {
    float* p = wbase + off; off += (n + 255) & ~(size_t)255; return p;
  };
  int* seqH = (int*)alloc(BATCH);
  int* seqB = (int*)alloc(BATCH);
  float* Bx[4]; float* bi[4]; _Float16* Wpk[4];
  const int din[4] = {E_, H_, E_, H_};
  for (int s = 0; s < 4; ++s) {
    Bx[s]  = alloc((size_t)din[s] * NG);
    bi[s]  = alloc(NG);
    Wpk[s] = (_Float16*)alloc(384 * 64 * 8 / 2);   // 384 KB fp16
  }
  float* st0 = alloc((size_t)BATCH * H_);
  float* hfH = alloc((size_t)BATCH * H_);
  float* hfB = alloc((size_t)BATCH * H_);
  float* Gc  = alloc((size_t)BATCH * CH * NG);
  float* Oc  = alloc((size_t)BATCH * CH * H_);
  (void)ws_size;

  // 1. pack weights
  for (int s = 0; s < 4; ++s) {
    int tot = din[s] * NG;
    pack_k<<<(tot + 255) / 256, 256, 0, stream>>>(
        W[s][0], W[s][1], W[s][2], W[s][3], din[s], Bx[s], bi[s]);
    pack_w<<<(384 * 64 + 255) / 256, 256, 0, stream>>>(
        W[s][0], W[s][2], din[s], Wpk[s]);
  }
  // 2. seqlens
  seq_k<<<BATCH, 256, 0, stream>>>(idsH, TH_, seqH);
  seq_k<<<BATCH, 256, 0, stream>>>(idsB, TB_, seqB);

  // 3. chunked pipeline per stream
  auto stream_run = [&](const int* ids, int T, int chs, const int* seq,
                        int l0, int l1, float* hf) {
    int rows = BATCH * chs;
    dim3 g(rows / 64, NG / 64);
    for (int t0 = 0; t0 < T; t0 += chs) {
      gemm_in<<<g, 256, 0, stream>>>(nullptr, ids, emb, Bx[l0], bi[l0], Gc,
                                     rows, E_, t0, chs, T);
      gru_mfma<<<NBLK, 512, 0, stream>>>(Gc, Wpk[l0], seq, Oc, st0, t0, chs);
      gemm_in<<<g, 256, 0, stream>>>(Oc, nullptr, nullptr, Bx[l1], bi[l1], Gc,
                                     rows, H_, 0, chs, T);
      gru_mfma<<<NBLK, 512, 0, stream>>>(Gc, Wpk[l1], seq, nullptr, hf, t0, chs);
    }
  };
  stream_run(idsH, TH_, CHH, seqH, 0, 1, hfH);
  stream_run(idsB, TB_, CH,  seqB, 2, 3, hfB);

  // 4. prediction head
  pred_k<<<1, 512, 0, stream>>>(hfH, hfB, Wp, bp, (float*)d_out);
}

// Round 4
// 6284.010 us; speedup vs baseline: 2.3707x; 2.3707x over previous
//
#include <hip/hip_runtime.h>
#include <cstdint>
#include <cstddef>

// Problem constants: V=50000, E=300, NF=1, H=256, B=128, TH=32, TB=512, NC=4.
#define H_    256
#define NG    768      // 512 gate cols (r|u) + 256 candidate cols, packed
#define BATCH 128
#define TH_   32
#define TB_   512
#define E_    300
#define RPB   16             // batch rows per gru block
#define NBLK  (BATCH / RPB)  // 8 row-groups; fused grid = 16 blocks

typedef _Float16 half8 __attribute__((ext_vector_type(8)));
typedef float    floatx4 __attribute__((ext_vector_type(4)));

// frag position of element (m, k) in packed-per-ktile LDS buffers:
// pos = (kt*64 + quad*16 + m)*8 + j,  kt=k>>5, quad=(k&31)>>3, j=k&7
__device__ __forceinline__ int fragpos(int m, int k) {
  return (((k >> 5) * 64) + (((k & 31) >> 3) * 16) + m) * 8 + (k & 7);
}

// ---------------------------------------------------------------------------
// Pack input-projection weights (fp32) + bias. j<512 -> Wg col j; else Wc.
// ---------------------------------------------------------------------------
__global__ __launch_bounds__(256) void pack_k(
    const float* __restrict__ Wg, const float* __restrict__ bg,
    const float* __restrict__ Wc, const float* __restrict__ bc, int din,
    float* __restrict__ Bx, float* __restrict__ bias)
{
  int idx = blockIdx.x * 256 + threadIdx.x;
  if (idx < NG) bias[idx] = (idx < 2 * H_) ? bg[idx] : bc[idx - 2 * H_];
  int tot = din * NG;
  if (idx >= tot) return;
  int k = idx / NG, j = idx % NG;
  float v = (j < 2 * H_) ? Wg[k * 2 * H_ + j] : Wc[k * H_ + (j - 2 * H_)];
  Bx[(size_t)k * NG + j] = v;
}

// ---------------------------------------------------------------------------
// Pack recurrent weights into fp16 MFMA B-fragment order (R3-validated).
// Tiles: [0,256): gate cols (Wg), nt=tile>>3, kt=tile&7, col base nt*16.
//        [256,384): candidate cols (Wc). 1 KB per tile (64 lanes x 16 B).
// B-frag: lane l, elem j -> W[k0 + (l>>4)*8 + j][n0 + (l&15)], k0=kt*32.
// ---------------------------------------------------------------------------
__global__ __launch_bounds__(256) void pack_w(
    const float* __restrict__ Wg, const float* __restrict__ Wc, int din,
    _Float16* __restrict__ wpk)
{
  int idx = blockIdx.x * 256 + threadIdx.x;
  if (idx >= 384 * 64) return;
  int tile = idx >> 6, lane = idx & 63;
  const float* W; int ncols, nt, kt;
  if (tile < 256) { nt = tile >> 3; kt = tile & 7; W = Wg; ncols = 2 * H_; }
  else { int tt = tile - 256; nt = tt >> 3; kt = tt & 7; W = Wc; ncols = H_; }
  int n = nt * 16 + (lane & 15);
  int kb = kt * 32 + (lane >> 4) * 8;
  _Float16* dst = wpk + ((size_t)(tile * 64 + lane)) * 8;
#pragma unroll
  for (int j = 0; j < 8; ++j)
    dst[j] = (_Float16)W[(size_t)(din + kb + j) * ncols + n];
}

// ---------------------------------------------------------------------------
// seqlen[b] = #nonzero ids in row b (valid steps form a prefix).
// ---------------------------------------------------------------------------
__global__ __launch_bounds__(256) void seq_k(const int* __restrict__ ids, int T,
                                             int* __restrict__ seq)
{
  __shared__ int red[256];
  int b = blockIdx.x, tid = threadIdx.x;
  int cnt = 0;
  for (int t = tid; t < T; t += 256) cnt += (ids[b * T + t] != 0) ? 1 : 0;
  red[tid] = cnt;
  __syncthreads();
  for (int s = 128; s > 0; s >>= 1) {
    if (tid < s) red[tid] += red[tid + s];
    __syncthreads();
  }
  if (tid == 0) seq[b] = red[0];
}

// ---------------------------------------------------------------------------
// Input-projection GEMM over a time-chunk (fp32):
//   G[(tl*BATCH + b)*NG + col] = A[row, :K] @ Bp[K, 768] + bias,
//   row = b*tc + tl (time-major G output for the persistent gru).
// ---------------------------------------------------------------------------
__global__ __launch_bounds__(256) void gemm_in(
    const float* __restrict__ Adir, const int* __restrict__ ids,
    const float* __restrict__ emb,
    const float* __restrict__ Bp, const float* __restrict__ bias,
    float* __restrict__ G, int nrows, int K, int t0, int tc, int T)
{
  __shared__ float As[16][68];
  __shared__ float Bs[16][64];
  const int tid = threadIdx.x;
  const int m0 = blockIdx.x * 64;
  const int n0 = blockIdx.y * 64;
  const int tm = (tid >> 4) * 4;
  const int tn = (tid & 15) * 4;
  const int la_r = tid >> 4;
  const int la_k = tid & 15;
  const int lb_n = tid & 63;
  const int lb_k = tid >> 6;
  float acc[4][4] = {{0.f}};

  for (int k0 = 0; k0 < K; k0 += 16) {
#pragma unroll
    for (int p = 0; p < 4; ++p) {
      int r = p * 16 + la_r;
      int row = m0 + r;
      int kg = k0 + la_k;
      float v = 0.f;
      if (row < nrows && kg < K) {
        if (Adir) v = Adir[(size_t)row * K + kg];
        else {
          int b = row / tc, tl = row % tc;
          v = emb[(size_t)ids[b * T + t0 + tl] * K + kg];
        }
      }
      As[la_k][r] = v;
    }
#pragma unroll
    for (int p = 0; p < 4; ++p) {
      int kl = p * 4 + lb_k;
      int kg = k0 + kl;
      Bs[kl][lb_n] = (kg < K) ? Bp[(size_t)kg * NG + n0 + lb_n] : 0.f;
    }
    __syncthreads();
#pragma unroll
    for (int kk = 0; kk < 16; ++kk) {
      float a0 = As[kk][tm + 0], a1 = As[kk][tm + 1];
      float a2 = As[kk][tm + 2], a3 = As[kk][tm + 3];
      float b0 = Bs[kk][tn + 0], b1 = Bs[kk][tn + 1];
      float b2 = Bs[kk][tn + 2], b3 = Bs[kk][tn + 3];
      acc[0][0] += a0 * b0; acc[0][1] += a0 * b1; acc[0][2] += a0 * b2; acc[0][3] += a0 * b3;
      acc[1][0] += a1 * b0; acc[1][1] += a1 * b1; acc[1][2] += a1 * b2; acc[1][3] += a1 * b3;
      acc[2][0] += a2 * b0; acc[2][1] += a2 * b1; acc[2][2] += a2 * b2; acc[2][3] += a2 * b3;
      acc[3][0] += a3 * b0; acc[3][1] += a3 * b1; acc[3][2] += a3 * b2; acc[3][3] += a3 * b3;
    }
    __syncthreads();
  }
#pragma unroll
  for (int i = 0; i < 4; ++i) {
    int row = m0 + tm + i;
    if (row < nrows) {
      int b = row / tc, tl = row - b * tc;
      float* gout = G + ((size_t)tl * BATCH + b) * NG + n0 + tn;
#pragma unroll
      for (int j = 0; j < 4; ++j)
        gout[j] = acc[i][j] + bias[n0 + tn + j];
    }
  }
}

// ---------------------------------------------------------------------------
// Persistent-weight fused GRU. Grid = 16 blocks x 512 thr.
// Blocks [0,8): layer A (G0/W0/out0/st0/t00); [8,16): layer B (G1/W1/st1/t01)
// -> layer-0 chunk c and layer-1 chunk c-1 run concurrently (software
// pipeline across chunks). Either side disabled by null G.
// All recurrent weights live in VGPRs (192/wave, loaded once). Per step:
// h (fp16 hi+lo, exact) roundtrips LDS in MFMA frag order; G staged
// double-buffered in LDS via coalesced float4 loads (time-major G layout).
// ---------------------------------------------------------------------------
__global__ __launch_bounds__(512, 2) void gru_pers(
    const float* __restrict__ G0, const _Float16* __restrict__ W0,
    const int* __restrict__ seq, float* __restrict__ out0,
    float* __restrict__ st0, int t00, int tc,
    const float* __restrict__ G1, const _Float16* __restrict__ W1,
    float* __restrict__ st1, int t01)
{
  __shared__ __align__(16) _Float16 hpk[2][4096];   // h hi/lo, frag order
  __shared__ __align__(16) _Float16 rpk[2][4096];   // r*h hi/lo, frag order
  __shared__ float uf[16][260];                     // u gate
  __shared__ __align__(16) float Gs[2][16][772];    // staged G, double-buffered
  __shared__ int seqL[16];

  const int bid = blockIdx.x;
  const float* G; const _Float16* Wsrc; float* outp; float* state; int t0, rg;
  if (bid < NBLK) { G = G0; Wsrc = W0; outp = out0; state = st0; t0 = t00; rg = bid; }
  else            { G = G1; Wsrc = W1; outp = nullptr; state = st1; t0 = t01; rg = bid - NBLK; }
  if (!G) return;

  const int tid = threadIdx.x;
  const int w = tid >> 6, lane = tid & 63;
  const int quad = lane >> 4, l15 = lane & 15;

  // --- resident weights: 48 x half8 = 192 VGPRs per wave -------------------
  half8 wg[4][8], wc2[2][8];
#pragma unroll
  for (int s = 0; s < 4; ++s)
#pragma unroll
    for (int kt = 0; kt < 8; ++kt)
      wg[s][kt] = *(const half8*)&Wsrc[(size_t)(((w * 4 + s) * 8 + kt) * 64 + lane) * 8];
#pragma unroll
  for (int s = 0; s < 2; ++s)
#pragma unroll
    for (int kt = 0; kt < 8; ++kt)
      wc2[s][kt] = *(const half8*)&Wsrc[(size_t)((256 + (w * 2 + s) * 8 + kt) * 64 + lane) * 8];

  if (tid < 16) seqL[tid] = seq[rg * RPB + tid];
  for (int idx = tid; idx < 4096; idx += 512) {
    int m = idx & 15, k = idx >> 4;
    float v = (t0 == 0) ? 0.f : state[(size_t)(rg * RPB + m) * H_ + k];
    _Float16 hi = (_Float16)v;
    int pos = fragpos(m, k);
    hpk[0][pos] = hi;
    hpk[1][pos] = (_Float16)(v - (float)hi);
  }
  __syncthreads();
  int Smax = 0;
#pragma unroll
  for (int i = 0; i < 16; ++i) Smax = max(Smax, seqL[i]);
  int steps = Smax - t0;
  if (steps < 0) steps = 0;
  if (steps > tc) steps = tc;

  const float* gbase = G + (size_t)rg * RPB * NG;   // + t*BATCH*NG per step
  auto stage = [&](int t, int buf) {
    const float* gp = gbase + (size_t)t * BATCH * NG;
#pragma unroll
    for (int i = 0; i < 6; ++i) {
      int idx = i * 512 + tid;               // 0..3071 chunks of 16B
      int row = idx / 192, cc = (idx - row * 192) * 4;
      floatx4 v = *(const floatx4*)&gp[(size_t)idx * 4];
      *(floatx4*)&Gs[buf][row][cc] = v;
    }
  };
  if (steps > 0) stage(0, 0);
  __syncthreads();

  for (int t = 0; t < steps; ++t) {
    const int tg = t0 + t, buf = t & 1;
    if (t + 1 < steps) stage(t + 1, buf ^ 1);   // prefetch next step's G
    // ---------------- phase A: 512 gate cols ----------------
    floatx4 acc[4] = {};
#pragma unroll
    for (int kt = 0; kt < 8; ++kt) {
      half8 ahi = *(const half8*)&hpk[0][(kt * 64 + lane) * 8];
      half8 alo = *(const half8*)&hpk[1][(kt * 64 + lane) * 8];
#pragma unroll
      for (int s = 0; s < 4; ++s) {
        acc[s] = __builtin_amdgcn_mfma_f32_16x16x32_f16(ahi, wg[s][kt], acc[s], 0, 0, 0);
        acc[s] = __builtin_amdgcn_mfma_f32_16x16x32_f16(alo, wg[s][kt], acc[s], 0, 0, 0);
      }
    }
    if (w < 4) {           // r gates: cols 0..255
#pragma unroll
      for (int s = 0; s < 4; ++s) {
        int k = w * 64 + s * 16 + l15;
#pragma unroll
        for (int r = 0; r < 4; ++r) {
          int row = quad * 4 + r;
          float pre = acc[s][r] + Gs[buf][row][k];
          float gate = 1.f / (1.f + __expf(-pre));
          int pos = fragpos(row, k);
          float hold = (float)hpk[0][pos] + (float)hpk[1][pos];
          float rh = gate * hold;
          _Float16 hi = (_Float16)rh;
          rpk[0][pos] = hi;
          rpk[1][pos] = (_Float16)(rh - (float)hi);
        }
      }
    } else {               // u gates: cols 256..511
#pragma unroll
      for (int s = 0; s < 4; ++s) {
        int k = (w - 4) * 64 + s * 16 + l15;
#pragma unroll
        for (int r = 0; r < 4; ++r) {
          int row = quad * 4 + r;
          float pre = acc[s][r] + Gs[buf][row][256 + k];
          uf[row][k] = 1.f / (1.f + __expf(-pre));
        }
      }
    }
    __syncthreads();
    // ---------------- phase B: 256 candidate cols ----------------
    floatx4 accB[2] = {};
#pragma unroll
    for (int kt = 0; kt < 8; ++kt) {
      half8 ahi = *(const half8*)&rpk[0][(kt * 64 + lane) * 8];
      half8 alo = *(const half8*)&rpk[1][(kt * 64 + lane) * 8];
#pragma unroll
      for (int s = 0; s < 2; ++s) {
        accB[s] = __builtin_amdgcn_mfma_f32_16x16x32_f16(ahi, wc2[s][kt], accB[s], 0, 0, 0);
        accB[s] = __builtin_amdgcn_mfma_f32_16x16x32_f16(alo, wc2[s][kt], accB[s], 0, 0, 0);
      }
    }
#pragma unroll
    for (int s = 0; s < 2; ++s) {
      int k = w * 32 + s * 16 + l15;
#pragma unroll
      for (int r = 0; r < 4; ++r) {
        int row = quad * 4 + r;
        float pre = accB[s][r] + Gs[buf][row][512 + k];
        float e2 = __expf(2.f * pre);
        float c = 1.f - 2.f / (1.f + e2);      // tanh
        int pos = fragpos(row, k);
        float hold = (float)hpk[0][pos] + (float)hpk[1][pos];
        float u = uf[row][k];
        float hn = u * hold + (1.f - u) * c;
        bool valid = tg < seqL[row];
        if (!valid) hn = hold;
        _Float16 hi = (_Float16)hn;
        hpk[0][pos] = hi;
        hpk[1][pos] = (_Float16)(hn - (float)hi);
        if (outp)
          outp[((size_t)(rg * RPB + row) * tc + t) * H_ + k] = valid ? hn : 0.f;
      }
    }
    __syncthreads();
  }
  for (int idx = tid; idx < 4096; idx += 512) {
    int m = idx & 15, k = idx >> 4;
    int pos = fragpos(m, k);
    state[(size_t)(rg * RPB + m) * H_ + k] = (float)hpk[0][pos] + (float)hpk[1][pos];
  }
}

// ---------------------------------------------------------------------------
// Final prediction: out[b, c] = [h_head | h_body] @ W_pred + b_pred.
// ---------------------------------------------------------------------------
__global__ __launch_bounds__(512) void pred_k(
    const float* __restrict__ hh, const float* __restrict__ hb,
    const float* __restrict__ Wp, const float* __restrict__ bpred,
    float* __restrict__ out)
{
  int tid = threadIdx.x;
  int b = tid >> 2, c = tid & 3;
  float acc = bpred[c];
  for (int k = 0; k < H_; ++k) acc += hh[b * H_ + k] * Wp[k * 4 + c];
  for (int k = 0; k < H_; ++k) acc += hb[b * H_ + k] * Wp[(H_ + k) * 4 + c];
  out[b * 4 + c] = acc;
}

// ---------------------------------------------------------------------------
extern "C" void kernel_launch(void* const* d_in, const int* in_sizes, int n_in,
                              void* d_out, int out_size, void* d_ws, size_t ws_size,
                              hipStream_t stream)
{
  (void)in_sizes; (void)n_in; (void)out_size;
  const int*   idsH = (const int*)  d_in[0];
  const int*   idsB = (const int*)  d_in[1];
  const float* emb  = (const float*)d_in[2];
  const float* Wp   = (const float*)d_in[3];
  const float* bp   = (const float*)d_in[4];
  const float* W[4][4];   // [hd0,hd1,bd0,bd1][Wg,bg,Wc,bc]
  for (int s = 0; s < 4; ++s)
    for (int q = 0; q < 4; ++q)
      W[s][q] = (const float*)d_in[5 + s * 4 + q];

  // choose time-chunk CH to fit ws_size (two G buffers for the pipeline)
  const size_t fixed_f = 1600000;
  int CH = 64;
  while (CH > 8 && (fixed_f + (size_t)BATCH * CH * (2 * NG + H_)) * 4 > ws_size)
    CH >>= 1;
  const int CHH = (CH < TH_) ? CH : TH_;

  float* wbase = (float*)d_ws;
  size_t off = 0;
  auto alloc = [&](size_t n) {
    float* p = wbase + off; off += (n + 255) & ~(size_t)255; return p;
  };
  int* seqH = (int*)alloc(BATCH);
  int* seqB = (int*)alloc(BATCH);
  float* Bx[4]; float* bi[4]; _Float16* Wpk[4];
  const int din[4] = {E_, H_, E_, H_};
  for (int s = 0; s < 4; ++s) {
    Bx[s]  = alloc((size_t)din[s] * NG);
    bi[s]  = alloc(NG);
    Wpk[s] = (_Float16*)alloc(384 * 64 * 8 / 2);   // 384 KB fp16
  }
  float* st0 = alloc((size_t)BATCH * H_);   // layer-0 carry (per stream, reused)
  float* hfH = alloc((size_t)BATCH * H_);   // head layer-1 carry/final
  float* hfB = alloc((size_t)BATCH * H_);   // body layer-1 carry/final
  float* Gc0 = alloc((size_t)BATCH * CH * NG);
  float* Gc1 = alloc((size_t)BATCH * CH * NG);
  float* Oc  = alloc((size_t)BATCH * CH * H_);
  (void)ws_size;

  // 1. pack weights
  for (int s = 0; s < 4; ++s) {
    int tot = din[s] * NG;
    pack_k<<<(tot + 255) / 256, 256, 0, stream>>>(
        W[s][0], W[s][1], W[s][2], W[s][3], din[s], Bx[s], bi[s]);
    pack_w<<<(384 * 64 + 255) / 256, 256, 0, stream>>>(
        W[s][0], W[s][2], din[s], Wpk[s]);
  }
  // 2. seqlens
  seq_k<<<BATCH, 256, 0, stream>>>(idsH, TH_, seqH);
  seq_k<<<BATCH, 256, 0, stream>>>(idsB, TB_, seqB);

  // 3. chunk-pipelined stream: fused dispatch runs L0(c) and L1(c-1)
  auto run_stream = [&](const int* ids, int T, int chs, const int* seq,
                        int l0, int l1, float* hf) {
    int nchunks = T / chs;
    int rows = BATCH * chs;
    dim3 g(rows / 64, NG / 64);
    for (int c = 0; c < nchunks; ++c) {
      int t0 = c * chs;
      gemm_in<<<g, 256, 0, stream>>>(nullptr, ids, emb, Bx[l0], bi[l0], Gc0,
                                     rows, E_, t0, chs, T);
      gru_pers<<<2 * NBLK, 512, 0, stream>>>(
          Gc0, Wpk[l0], seq, Oc, st0, t0, chs,
          (c > 0) ? Gc1 : nullptr, Wpk[l1], hf, (c - 1) * chs);
      gemm_in<<<g, 256, 0, stream>>>(Oc, nullptr, nullptr, Bx[l1], bi[l1], Gc1,
                                     rows, H_, 0, chs, T);
    }
    // drain: last layer-1 chunk
    gru_pers<<<2 * NBLK, 512, 0, stream>>>(
        nullptr, Wpk[l0], seq, nullptr, st0, 0, chs,
        Gc1, Wpk[l1], hf, (nchunks - 1) * chs);
  };
  run_stream(idsH, TH_, CHH, seqH, 0, 1, hfH);   // headline (hd0, hd1)
  run_stream(idsB, TB_, CH,  seqB, 2, 3, hfB);   // body     (bd0, bd1)

  // 4. prediction head
  pred_k<<<1, 512, 0, stream>>>(hfH, hfB, Wp, bp, (float*)d_out);
}

// Round 5
// 5545.026 us; speedup vs baseline: 2.6867x; 1.1333x over previous
//
#include <hip/hip_runtime.h>
#include <cstdint>
#include <cstddef>

// Problem constants: V=50000, E=300, NF=1, H=256, B=128, TH=32, TB=512, NC=4.
#define H_    256
#define NG    768      // 512 gate cols (r|u) + 256 candidate cols, packed
#define BATCH 128
#define TH_   32
#define TB_   512
#define E_    300
#define RPB   16             // batch rows per gru block
#define NBLK  (BATCH / RPB)  // 8 row-groups; fused grid = 16 blocks

typedef _Float16 half8 __attribute__((ext_vector_type(8)));
typedef float    floatx4 __attribute__((ext_vector_type(4)));

// frag position of element (m, k) in packed-per-ktile LDS buffers:
// pos = (kt*64 + quad*16 + m)*8 + j,  kt=k>>5, quad=(k&31)>>3, j=k&7
__device__ __forceinline__ int fragpos(int m, int k) {
  return (((k >> 5) * 64) + (((k & 31) >> 3) * 16) + m) * 8 + (k & 7);
}

// ---------------------------------------------------------------------------
// Pack input-projection weights (fp32) + bias. j<512 -> Wg col j; else Wc.
// ---------------------------------------------------------------------------
__global__ __launch_bounds__(256) void pack_k(
    const float* __restrict__ Wg, const float* __restrict__ bg,
    const float* __restrict__ Wc, const float* __restrict__ bc, int din,
    float* __restrict__ Bx, float* __restrict__ bias)
{
  int idx = blockIdx.x * 256 + threadIdx.x;
  if (idx < NG) bias[idx] = (idx < 2 * H_) ? bg[idx] : bc[idx - 2 * H_];
  int tot = din * NG;
  if (idx >= tot) return;
  int k = idx / NG, j = idx % NG;
  float v = (j < 2 * H_) ? Wg[k * 2 * H_ + j] : Wc[k * H_ + (j - 2 * H_)];
  Bx[(size_t)k * NG + j] = v;
}

// ---------------------------------------------------------------------------
// Pack recurrent weights into fp16 MFMA B-fragment order (R3-validated).
// Tiles: [0,256): gate cols (Wg), nt=tile>>3, kt=tile&7, col base nt*16.
//        [256,384): candidate cols (Wc). 1 KB per tile (64 lanes x 16 B).
// B-frag: lane l, elem j -> W[k0 + (l>>4)*8 + j][n0 + (l&15)], k0=kt*32.
// ---------------------------------------------------------------------------
__global__ __launch_bounds__(256) void pack_w(
    const float* __restrict__ Wg, const float* __restrict__ Wc, int din,
    _Float16* __restrict__ wpk)
{
  int idx = blockIdx.x * 256 + threadIdx.x;
  if (idx >= 384 * 64) return;
  int tile = idx >> 6, lane = idx & 63;
  const float* W; int ncols, nt, kt;
  if (tile < 256) { nt = tile >> 3; kt = tile & 7; W = Wg; ncols = 2 * H_; }
  else { int tt = tile - 256; nt = tt >> 3; kt = tt & 7; W = Wc; ncols = H_; }
  int n = nt * 16 + (lane & 15);
  int kb = kt * 32 + (lane >> 4) * 8;
  _Float16* dst = wpk + ((size_t)(tile * 64 + lane)) * 8;
#pragma unroll
  for (int j = 0; j < 8; ++j)
    dst[j] = (_Float16)W[(size_t)(din + kb + j) * ncols + n];
}

// ---------------------------------------------------------------------------
// seqlen[b] = #nonzero ids in row b (valid steps form a prefix).
// ---------------------------------------------------------------------------
__global__ __launch_bounds__(256) void seq_k(const int* __restrict__ ids, int T,
                                             int* __restrict__ seq)
{
  __shared__ int red[256];
  int b = blockIdx.x, tid = threadIdx.x;
  int cnt = 0;
  for (int t = tid; t < T; t += 256) cnt += (ids[b * T + t] != 0) ? 1 : 0;
  red[tid] = cnt;
  __syncthreads();
  for (int s = 128; s > 0; s >>= 1) {
    if (tid < s) red[tid] += red[tid + s];
    __syncthreads();
  }
  if (tid == 0) seq[b] = red[0];
}

// ---------------------------------------------------------------------------
// Input-projection GEMM over a time-chunk (fp32):
//   G[(tl*BATCH + b)*NG + col] = A[row, :K] @ Bp[K, 768] + bias,
//   row = b*tc + tl (time-major G output for the persistent gru).
// ---------------------------------------------------------------------------
__global__ __launch_bounds__(256) void gemm_in(
    const float* __restrict__ Adir, const int* __restrict__ ids,
    const float* __restrict__ emb,
    const float* __restrict__ Bp, const float* __restrict__ bias,
    float* __restrict__ G, int nrows, int K, int t0, int tc, int T)
{
  __shared__ float As[16][68];
  __shared__ float Bs[16][64];
  const int tid = threadIdx.x;
  const int m0 = blockIdx.x * 64;
  const int n0 = blockIdx.y * 64;
  const int tm = (tid >> 4) * 4;
  const int tn = (tid & 15) * 4;
  const int la_r = tid >> 4;
  const int la_k = tid & 15;
  const int lb_n = tid & 63;
  const int lb_k = tid >> 6;
  float acc[4][4] = {{0.f}};

  for (int k0 = 0; k0 < K; k0 += 16) {
#pragma unroll
    for (int p = 0; p < 4; ++p) {
      int r = p * 16 + la_r;
      int row = m0 + r;
      int kg = k0 + la_k;
      float v = 0.f;
      if (row < nrows && kg < K) {
        if (Adir) v = Adir[(size_t)row * K + kg];
        else {
          int b = row / tc, tl = row % tc;
          v = emb[(size_t)ids[b * T + t0 + tl] * K + kg];
        }
      }
      As[la_k][r] = v;
    }
#pragma unroll
    for (int p = 0; p < 4; ++p) {
      int kl = p * 4 + lb_k;
      int kg = k0 + kl;
      Bs[kl][lb_n] = (kg < K) ? Bp[(size_t)kg * NG + n0 + lb_n] : 0.f;
    }
    __syncthreads();
#pragma unroll
    for (int kk = 0; kk < 16; ++kk) {
      float a0 = As[kk][tm + 0], a1 = As[kk][tm + 1];
      float a2 = As[kk][tm + 2], a3 = As[kk][tm + 3];
      float b0 = Bs[kk][tn + 0], b1 = Bs[kk][tn + 1];
      float b2 = Bs[kk][tn + 2], b3 = Bs[kk][tn + 3];
      acc[0][0] += a0 * b0; acc[0][1] += a0 * b1; acc[0][2] += a0 * b2; acc[0][3] += a0 * b3;
      acc[1][0] += a1 * b0; acc[1][1] += a1 * b1; acc[1][2] += a1 * b2; acc[1][3] += a1 * b3;
      acc[2][0] += a2 * b0; acc[2][1] += a2 * b1; acc[2][2] += a2 * b2; acc[2][3] += a2 * b3;
      acc[3][0] += a3 * b0; acc[3][1] += a3 * b1; acc[3][2] += a3 * b2; acc[3][3] += a3 * b3;
    }
    __syncthreads();
  }
#pragma unroll
  for (int i = 0; i < 4; ++i) {
    int row = m0 + tm + i;
    if (row < nrows) {
      int b = row / tc, tl = row - b * tc;
      float* gout = G + ((size_t)tl * BATCH + b) * NG + n0 + tn;
#pragma unroll
      for (int j = 0; j < 4; ++j)
        gout[j] = acc[i][j] + bias[n0 + tn + j];
    }
  }
}

// ---------------------------------------------------------------------------
// Persistent-weight fused GRU. Grid = 16 blocks x 512 thr, ONE block per CU
// (launch_bounds(512,1) -> 256-VGPR cap so the 192 weight VGPRs stay
// resident; R4's (512,2) capped at 128 and the compiler re-streamed weights
// from L2 every step — the 7.9us/step bug).
// Blocks [0,8): layer A (G0/W0/out0/st0/t00); [8,16): layer B (G1/W1/st1/t01)
// -> layer-0 chunk c and layer-1 chunk c-1 run concurrently.
// Per step: h (fp16 hi+lo, exact) roundtrips LDS in MFMA frag order; G staged
// double-buffered in LDS via async global_load_lds (time-major G, 16B/lane,
// zero data VGPRs; Gs unpadded — contiguity required by global_load_lds).
// ---------------------------------------------------------------------------
__global__ __launch_bounds__(512, 1) void gru_pers(
    const float* __restrict__ G0, const _Float16* __restrict__ W0,
    const int* __restrict__ seq, float* __restrict__ out0,
    float* __restrict__ st0, int t00, int tc,
    const float* __restrict__ G1, const _Float16* __restrict__ W1,
    float* __restrict__ st1, int t01)
{
  __shared__ __align__(16) _Float16 hpk[2][4096];   // h hi/lo, frag order
  __shared__ __align__(16) _Float16 rpk[2][4096];   // r*h hi/lo, frag order
  __shared__ float uf[16][260];                     // u gate (+4 pad)
  __shared__ __align__(16) float Gs[2][16][768];    // staged G (UNPADDED)
  __shared__ int seqL[16];

  const int bid = blockIdx.x;
  const float* G; const _Float16* Wsrc; float* outp; float* state; int t0, rg;
  if (bid < NBLK) { G = G0; Wsrc = W0; outp = out0; state = st0; t0 = t00; rg = bid; }
  else            { G = G1; Wsrc = W1; outp = nullptr; state = st1; t0 = t01; rg = bid - NBLK; }
  if (!G) return;

  const int tid = threadIdx.x;
  const int w = tid >> 6, lane = tid & 63;
  const int quad = lane >> 4, l15 = lane & 15;

  // --- resident weights: 48 x half8 = 192 VGPRs per wave -------------------
  half8 wg[4][8], wc2[2][8];
#pragma unroll
  for (int s = 0; s < 4; ++s)
#pragma unroll
    for (int kt = 0; kt < 8; ++kt)
      wg[s][kt] = *(const half8*)&Wsrc[(size_t)(((w * 4 + s) * 8 + kt) * 64 + lane) * 8];
#pragma unroll
  for (int s = 0; s < 2; ++s)
#pragma unroll
    for (int kt = 0; kt < 8; ++kt)
      wc2[s][kt] = *(const half8*)&Wsrc[(size_t)((256 + (w * 2 + s) * 8 + kt) * 64 + lane) * 8];

  if (tid < 16) seqL[tid] = seq[rg * RPB + tid];
  for (int idx = tid; idx < 4096; idx += 512) {
    int m = idx & 15, k = idx >> 4;
    float v = (t0 == 0) ? 0.f : state[(size_t)(rg * RPB + m) * H_ + k];
    _Float16 hi = (_Float16)v;
    int pos = fragpos(m, k);
    hpk[0][pos] = hi;
    hpk[1][pos] = (_Float16)(v - (float)hi);
  }
  __syncthreads();
  int Smax = 0;
#pragma unroll
  for (int i = 0; i < 16; ++i) Smax = max(Smax, seqL[i]);
  int steps = Smax - t0;
  if (steps < 0) steps = 0;
  if (steps > tc) steps = tc;

  // async staging: wave w copies segments w*6..w*6+5 (1 KB each, 16 B/lane)
  const float* gblk = G + (size_t)rg * RPB * NG;    // + t*BATCH*NG per step
  auto stage = [&](int t, int buf) {
    const float* gp = gblk + (size_t)t * BATCH * NG;
#pragma unroll
    for (int i = 0; i < 6; ++i) {
      int seg = w * 6 + i;                           // 0..47
      const float* gsrc = gp + (size_t)seg * 256 + lane * 4;
      __builtin_amdgcn_global_load_lds(
          (const __attribute__((address_space(1))) unsigned int*)gsrc,
          (__attribute__((address_space(3))) unsigned int*)&Gs[buf][0][seg * 256],
          16, 0, 0);
    }
  };
  if (steps > 0) stage(0, 0);
  __syncthreads();

  for (int t = 0; t < steps; ++t) {
    const int tg = t0 + t, buf = t & 1;
    if (t + 1 < steps) stage(t + 1, buf ^ 1);   // async prefetch next step's G
    // ---------------- phase A: 512 gate cols ----------------
    floatx4 acc[4] = {};
#pragma unroll
    for (int kt = 0; kt < 8; ++kt) {
      half8 ahi = *(const half8*)&hpk[0][(kt * 64 + lane) * 8];
      half8 alo = *(const half8*)&hpk[1][(kt * 64 + lane) * 8];
#pragma unroll
      for (int s = 0; s < 4; ++s) {
        acc[s] = __builtin_amdgcn_mfma_f32_16x16x32_f16(ahi, wg[s][kt], acc[s], 0, 0, 0);
        acc[s] = __builtin_amdgcn_mfma_f32_16x16x32_f16(alo, wg[s][kt], acc[s], 0, 0, 0);
      }
    }
    if (w < 4) {           // r gates: cols 0..255
#pragma unroll
      for (int s = 0; s < 4; ++s) {
        int k = w * 64 + s * 16 + l15;
#pragma unroll
        for (int r = 0; r < 4; ++r) {
          int row = quad * 4 + r;
          float pre = acc[s][r] + Gs[buf][row][k];
          float gate = 1.f / (1.f + __expf(-pre));
          int pos = fragpos(row, k);
          float hold = (float)hpk[0][pos] + (float)hpk[1][pos];
          float rh = gate * hold;
          _Float16 hi = (_Float16)rh;
          rpk[0][pos] = hi;
          rpk[1][pos] = (_Float16)(rh - (float)hi);
        }
      }
    } else {               // u gates: cols 256..511
#pragma unroll
      for (int s = 0; s < 4; ++s) {
        int k = (w - 4) * 64 + s * 16 + l15;
#pragma unroll
        for (int r = 0; r < 4; ++r) {
          int row = quad * 4 + r;
          float pre = acc[s][r] + Gs[buf][row][256 + k];
          uf[row][k] = 1.f / (1.f + __expf(-pre));
        }
      }
    }
    __syncthreads();
    // ---------------- phase B: 256 candidate cols ----------------
    floatx4 accB[2] = {};
#pragma unroll
    for (int kt = 0; kt < 8; ++kt) {
      half8 ahi = *(const half8*)&rpk[0][(kt * 64 + lane) * 8];
      half8 alo = *(const half8*)&rpk[1][(kt * 64 + lane) * 8];
#pragma unroll
      for (int s = 0; s < 2; ++s) {
        accB[s] = __builtin_amdgcn_mfma_f32_16x16x32_f16(ahi, wc2[s][kt], accB[s], 0, 0, 0);
        accB[s] = __builtin_amdgcn_mfma_f32_16x16x32_f16(alo, wc2[s][kt], accB[s], 0, 0, 0);
      }
    }
#pragma unroll
    for (int s = 0; s < 2; ++s) {
      int k = w * 32 + s * 16 + l15;
#pragma unroll
      for (int r = 0; r < 4; ++r) {
        int row = quad * 4 + r;
        float pre = accB[s][r] + Gs[buf][row][512 + k];
        float e2 = __expf(2.f * pre);
        float c = 1.f - 2.f / (1.f + e2);      // tanh
        int pos = fragpos(row, k);
        float hold = (float)hpk[0][pos] + (float)hpk[1][pos];
        float u = uf[row][k];
        float hn = u * hold + (1.f - u) * c;
        bool valid = tg < seqL[row];
        if (!valid) hn = hold;
        _Float16 hi = (_Float16)hn;
        hpk[0][pos] = hi;
        hpk[1][pos] = (_Float16)(hn - (float)hi);
        if (outp)
          outp[((size_t)(rg * RPB + row) * tc + t) * H_ + k] = valid ? hn : 0.f;
      }
    }
    __syncthreads();
  }
  for (int idx = tid; idx < 4096; idx += 512) {
    int m = idx & 15, k = idx >> 4;
    int pos = fragpos(m, k);
    state[(size_t)(rg * RPB + m) * H_ + k] = (float)hpk[0][pos] + (float)hpk[1][pos];
  }
}

// ---------------------------------------------------------------------------
// Final prediction: out[b, c] = [h_head | h_body] @ W_pred + b_pred.
// ---------------------------------------------------------------------------
__global__ __launch_bounds__(512) void pred_k(
    const float* __restrict__ hh, const float* __restrict__ hb,
    const float* __restrict__ Wp, const float* __restrict__ bpred,
    float* __restrict__ out)
{
  int tid = threadIdx.x;
  int b = tid >> 2, c = tid & 3;
  float acc = bpred[c];
  for (int k = 0; k < H_; ++k) acc += hh[b * H_ + k] * Wp[k * 4 + c];
  for (int k = 0; k < H_; ++k) acc += hb[b * H_ + k] * Wp[(H_ + k) * 4 + c];
  out[b * 4 + c] = acc;
}

// ---------------------------------------------------------------------------
extern "C" void kernel_launch(void* const* d_in, const int* in_sizes, int n_in,
                              void* d_out, int out_size, void* d_ws, size_t ws_size,
                              hipStream_t stream)
{
  (void)in_sizes; (void)n_in; (void)out_size;
  const int*   idsH = (const int*)  d_in[0];
  const int*   idsB = (const int*)  d_in[1];
  const float* emb  = (const float*)d_in[2];
  const float* Wp   = (const float*)d_in[3];
  const float* bp   = (const float*)d_in[4];
  const float* W[4][4];   // [hd0,hd1,bd0,bd1][Wg,bg,Wc,bc]
  for (int s = 0; s < 4; ++s)
    for (int q = 0; q < 4; ++q)
      W[s][q] = (const float*)d_in[5 + s * 4 + q];

  // choose time-chunk CH to fit ws_size (two G buffers for the pipeline)
  const size_t fixed_f = 1600000;
  int CH = 64;
  while (CH > 8 && (fixed_f + (size_t)BATCH * CH * (2 * NG + H_)) * 4 > ws_size)
    CH >>= 1;
  const int CHH = (CH < TH_) ? CH : TH_;

  float* wbase = (float*)d_ws;
  size_t off = 0;
  auto alloc = [&](size_t n) {
    float* p = wbase + off; off += (n + 255) & ~(size_t)255; return p;
  };
  int* seqH = (int*)alloc(BATCH);
  int* seqB = (int*)alloc(BATCH);
  float* Bx[4]; float* bi[4]; _Float16* Wpk[4];
  const int din[4] = {E_, H_, E_, H_};
  for (int s = 0; s < 4; ++s) {
    Bx[s]  = alloc((size_t)din[s] * NG);
    bi[s]  = alloc(NG);
    Wpk[s] = (_Float16*)alloc(384 * 64 * 8 / 2);   // 384 KB fp16
  }
  float* st0 = alloc((size_t)BATCH * H_);   // layer-0 carry (per stream, reused)
  float* hfH = alloc((size_t)BATCH * H_);   // head layer-1 carry/final
  float* hfB = alloc((size_t)BATCH * H_);   // body layer-1 carry/final
  float* Gc0 = alloc((size_t)BATCH * CH * NG);
  float* Gc1 = alloc((size_t)BATCH * CH * NG);
  float* Oc  = alloc((size_t)BATCH * CH * H_);
  (void)ws_size;

  // 1. pack weights
  for (int s = 0; s < 4; ++s) {
    int tot = din[s] * NG;
    pack_k<<<(tot + 255) / 256, 256, 0, stream>>>(
        W[s][0], W[s][1], W[s][2], W[s][3], din[s], Bx[s], bi[s]);
    pack_w<<<(384 * 64 + 255) / 256, 256, 0, stream>>>(
        W[s][0], W[s][2], din[s], Wpk[s]);
  }
  // 2. seqlens
  seq_k<<<BATCH, 256, 0, stream>>>(idsH, TH_, seqH);
  seq_k<<<BATCH, 256, 0, stream>>>(idsB, TB_, seqB);

  // 3. chunk-pipelined stream: fused dispatch runs L0(c) and L1(c-1)
  auto run_stream = [&](const int* ids, int T, int chs, const int* seq,
                        int l0, int l1, float* hf) {
    int nchunks = T / chs;
    int rows = BATCH * chs;
    dim3 g(rows / 64, NG / 64);
    for (int c = 0; c < nchunks; ++c) {
      int t0 = c * chs;
      gemm_in<<<g, 256, 0, stream>>>(nullptr, ids, emb, Bx[l0], bi[l0], Gc0,
                                     rows, E_, t0, chs, T);
      gru_pers<<<2 * NBLK, 512, 0, stream>>>(
          Gc0, Wpk[l0], seq, Oc, st0, t0, chs,
          (c > 0) ? Gc1 : nullptr, Wpk[l1], hf, (c - 1) * chs);
      gemm_in<<<g, 256, 0, stream>>>(Oc, nullptr, nullptr, Bx[l1], bi[l1], Gc1,
                                     rows, H_, 0, chs, T);
    }
    // drain: last layer-1 chunk
    gru_pers<<<2 * NBLK, 512, 0, stream>>>(
        nullptr, Wpk[l0], seq, nullptr, st0, 0, chs,
        Gc1, Wpk[l1], hf, (nchunks - 1) * chs);
  };
  run_stream(idsH, TH_, CHH, seqH, 0, 1, hfH);   // headline (hd0, hd1)
  run_stream(idsB, TB_, CH,  seqB, 2, 3, hfB);   // body     (bd0, bd1)

  // 4. prediction head
  pred_k<<<1, 512, 0, stream>>>(hfH, hfB, Wp, bp, (float*)d_out);
}